// Round 4
// baseline (1731.603 us; speedup 1.0000x reference)
//
#include <hip/hip_runtime.h>

typedef _Float16 f16;
typedef _Float16 f16x2 __attribute__((ext_vector_type(2)));
typedef _Float16 f16x8 __attribute__((ext_vector_type(8)));
typedef float f32x4 __attribute__((ext_vector_type(4)));
typedef unsigned int u32;

// ---------- sizes ----------
// B=256, W=512, FEAT=128, TIME=32, OV=32, IN=192, HG=256, HL=128, OG=128, OL=64
// rows = B*W = 131072. Time processed in NCHUNK chunks of TC steps.
static constexpr size_t NROWS = 131072;
static constexpr int TC = 64;
static constexpr int NCHUNK = 8;   // 512 / TC
static constexpr size_t CROWS = 256 * TC;  // rows per chunk = 16384

// inp is T-MAJOR: row (t*256 + b), 192 f16 each. xbuf likewise within a chunk.
static constexpr size_t O_INP = 0;                                   // inp f16 [131072][192] t-major
static constexpr size_t SZ_INP = NROWS * 192 * 2;                    // 50.3 MB
static constexpr size_t O_XB  = O_INP + SZ_INP;                      // xih chunk f16 [16384][1152]
static constexpr size_t SZ_XB = CROWS * 1152 * 2;                    // 37.7 MB
static constexpr size_t O_HG  = O_XB + SZ_XB;                        // hg_seq f16 [131072][256] b-major
static constexpr size_t SZ_HG = NROWS * 256 * 2;                     // 67.1 MB
static constexpr size_t O_HL  = O_HG + SZ_HG;                        // hl_seq f16 [131072][128] b-major
static constexpr size_t SZ_HL = NROWS * 128 * 2;                     // 33.6 MB
static constexpr size_t O_WF  = O_HL + SZ_HL;                        // wfused f16 [1152][192]
static constexpr size_t SZ_WF = 1152 * 192 * 2;
static constexpr size_t O_BF  = O_WF + SZ_WF;                        // biasf f32 [1152]
static constexpr size_t SZ_BF = 1152 * 4;
static constexpr size_t O_WHG = O_BF + SZ_BF;                        // whh_g packed [128][768] u32
static constexpr size_t SZ_WHG = 128 * 768 * 4;
static constexpr size_t O_WHL = O_WHG + SZ_WHG;                      // whh_l packed [64][384] u32
static constexpr size_t SZ_WHL = 64 * 384 * 4;
static constexpr size_t O_WG  = O_WHL + SZ_WHL;                      // wg f16 [128][256]
static constexpr size_t SZ_WG = 128 * 256 * 2;
static constexpr size_t O_WL  = O_WG + SZ_WG;                        // wl f16 [64][128]
static constexpr size_t SZ_WL = 64 * 128 * 2;
static constexpr size_t O_HGF = O_WL + SZ_WL;                        // h-state global f32 [256][256]
static constexpr size_t SZ_HGF = 256 * 256 * 4;
static constexpr size_t O_HGP = O_HGF + SZ_HGF;                      // h-state global packed u32 [256][128]
static constexpr size_t SZ_HGP = 256 * 128 * 4;
static constexpr size_t O_HLF = O_HGP + SZ_HGP;                      // h-state local f32 [256][128]
static constexpr size_t SZ_HLF = 256 * 128 * 4;
static constexpr size_t O_HLP = O_HLF + SZ_HLF;                      // h-state local packed u32 [256][64]
static constexpr size_t SZ_HLP = 256 * 64 * 4;
static constexpr size_t WS_NEED = O_HLP + SZ_HLP;                    // ~181.5 MiB

// ---------- helpers ----------
__device__ inline u32 pk2f(float lo, float hi) {
  f16x2 t; t.x = (f16)lo; t.y = (f16)hi;
  return __builtin_bit_cast(u32, t);
}

#if defined(__has_builtin)
#if __has_builtin(__builtin_amdgcn_fdot2)
#define HAVE_FDOT2 1
#endif
#endif

__device__ inline float dot2f(u32 w, u32 h, float c) {
#ifdef HAVE_FDOT2
  return __builtin_amdgcn_fdot2(__builtin_bit_cast(f16x2, w),
                                __builtin_bit_cast(f16x2, h), c, false);
#else
  f16x2 a = __builtin_bit_cast(f16x2, w);
  f16x2 b = __builtin_bit_cast(f16x2, h);
  return c + (float)a.x * (float)b.x + (float)a.y * (float)b.y;
#endif
}

__device__ inline float sigf(float x) { return 1.f / (1.f + __expf(-x)); }
__device__ inline float tanhf_fast(float x) { return 1.f - 2.f / (1.f + __expf(2.f * x)); }

// ---------- prep: weight conversion/packing ----------
__global__ void prep_k(const float* __restrict__ Wih_g, const float* __restrict__ Wih_l,
                       const float* __restrict__ bih_g, const float* __restrict__ bih_l,
                       const float* __restrict__ Whh_g, const float* __restrict__ Whh_l,
                       const float* __restrict__ Wg, const float* __restrict__ Wl,
                       f16* __restrict__ wfused, float* __restrict__ biasf,
                       u32* __restrict__ whhg, u32* __restrict__ whhl,
                       f16* __restrict__ wg16, f16* __restrict__ wl16) {
  const int tid = blockIdx.x * blockDim.x + threadIdx.x;
  const int stride = gridDim.x * blockDim.x;
  for (int i = tid; i < 1152 * 192; i += stride) {
    int r = i / 192;
    wfused[i] = (f16)(r < 768 ? Wih_g[i] : Wih_l[i - 768 * 192]);
  }
  for (int i = tid; i < 1152; i += stride)
    biasf[i] = (i < 768) ? bih_g[i] : bih_l[i - 768];
  for (int i = tid; i < 128 * 768; i += stride) {
    int k2 = i / 768, r = i % 768;
    whhg[i] = pk2f(Whh_g[r * 256 + 2 * k2], Whh_g[r * 256 + 2 * k2 + 1]);
  }
  for (int i = tid; i < 64 * 384; i += stride) {
    int k2 = i / 384, r = i % 384;
    whhl[i] = pk2f(Whh_l[r * 128 + 2 * k2], Whh_l[r * 128 + 2 * k2 + 1]);
  }
  for (int i = tid; i < 128 * 256; i += stride) wg16[i] = (f16)Wg[i];
  for (int i = tid; i < 64 * 128; i += stride) wl16[i] = (f16)Wl[i];
}

// ---------- encoder: ov = silu(ov_in@W1^T+b1)@W2^T+b2; write inp=[f|delta|ov] f16 t-major ----------
__global__ __launch_bounds__(256) void encoder_k(
    const float* __restrict__ f_seq, const float* __restrict__ delta,
    const float* __restrict__ ovin, const float* __restrict__ W1,
    const float* __restrict__ b1, const float* __restrict__ W2,
    const float* __restrict__ b2, f16* __restrict__ inp) {
  __shared__ float sW1[2048], sW2[2048], sb1[64], sb2[32];
  for (int i = threadIdx.x; i < 2048; i += 256) { sW1[i] = W1[i]; sW2[i] = W2[i]; }
  if (threadIdx.x < 64) sb1[threadIdx.x] = b1[threadIdx.x];
  if (threadIdx.x < 32) sb2[threadIdx.x] = b2[threadIdx.x];
  __syncthreads();
  const size_t rid = (size_t)blockIdx.x * 256 + threadIdx.x;  // source row b*512+t
  const size_t b = rid >> 9, t = rid & 511;

  float ov[32];
  const float4* ovp = reinterpret_cast<const float4*>(ovin + rid * 32);
#pragma unroll
  for (int i = 0; i < 8; ++i) {
    float4 v = ovp[i];
    ov[4 * i] = v.x; ov[4 * i + 1] = v.y; ov[4 * i + 2] = v.z; ov[4 * i + 3] = v.w;
  }
  float hb[64];
#pragma unroll
  for (int j = 0; j < 64; ++j) {
    float s = sb1[j];
#pragma unroll
    for (int k = 0; k < 32; ++k) s += sW1[j * 32 + k] * ov[k];
    hb[j] = s * sigf(s);   // SiLU
  }
  // destination row is t-major: t*256 + b
  u32* orow = reinterpret_cast<u32*>(inp + (t * 256 + b) * 192);
  const float4* fp = reinterpret_cast<const float4*>(f_seq + rid * 128);
#pragma unroll
  for (int i = 0; i < 32; ++i) {
    float4 v = fp[i];
    orow[2 * i] = pk2f(v.x, v.y); orow[2 * i + 1] = pk2f(v.z, v.w);
  }
  const float4* dp = reinterpret_cast<const float4*>(delta + rid * 32);
#pragma unroll
  for (int i = 0; i < 8; ++i) {
    float4 v = dp[i];
    orow[64 + 2 * i] = pk2f(v.x, v.y); orow[64 + 2 * i + 1] = pk2f(v.z, v.w);
  }
#pragma unroll
  for (int p = 0; p < 16; ++p) {
    float s0 = sb2[2 * p], s1 = sb2[2 * p + 1];
#pragma unroll
    for (int j = 0; j < 64; ++j) {
      s0 += sW2[(2 * p) * 64 + j] * hb[j];
      s1 += sW2[(2 * p + 1) * 64 + j] * hb[j];
    }
    orow[80 + p] = pk2f(s0, s1);
  }
}

// ---------- MFMA f16 GEMM: C[M][N] = A[M][K] @ Bw[N][K]^T + bias ----------
// 128x128 tile, 256 threads (4 waves, 2x2), padded LDS stride 40 halves (80B).
template <int K, int NROWSB, int NVALID, bool OUTF16, int LDC>
__global__ __launch_bounds__(256, 2) void gemm_f16k(
    const f16* __restrict__ A, const f16* __restrict__ Bw,
    const float* __restrict__ bias, void* __restrict__ Cout) {
  __shared__ alignas(16) f16 At[128 * 40];
  __shared__ alignas(16) f16 Bt[128 * 40];
  const int n0 = blockIdx.x * 128;
  const int m0 = blockIdx.y * 128;
  const int tid = threadIdx.x;
  const int l = tid & 63;
  const int w = tid >> 6;
  const int wm = w >> 1, wn = w & 1;
  const int srow = tid >> 2, schunk = tid & 3;

  f32x4 acc[4][4] = {};

  for (int k0 = 0; k0 < K; k0 += 32) {
#pragma unroll
    for (int hh = 0; hh < 2; ++hh) {
      int row = srow + hh * 64;
      uint4 av = *reinterpret_cast<const uint4*>(A + (size_t)(m0 + row) * K + k0 + schunk * 8);
      *reinterpret_cast<uint4*>(&At[row * 40 + schunk * 8]) = av;
      int nr = n0 + row;
      uint4 bv = make_uint4(0u, 0u, 0u, 0u);
      if (nr < NROWSB)
        bv = *reinterpret_cast<const uint4*>(Bw + (size_t)nr * K + k0 + schunk * 8);
      *reinterpret_cast<uint4*>(&Bt[row * 40 + schunk * 8]) = bv;
    }
    __syncthreads();
    f16x8 af[4], bf[4];
#pragma unroll
    for (int i = 0; i < 4; ++i) {
      af[i] = *reinterpret_cast<const f16x8*>(&At[(wm * 64 + i * 16 + (l & 15)) * 40 + (l >> 4) * 8]);
      bf[i] = *reinterpret_cast<const f16x8*>(&Bt[(wn * 64 + i * 16 + (l & 15)) * 40 + (l >> 4) * 8]);
    }
#pragma unroll
    for (int mi = 0; mi < 4; ++mi)
#pragma unroll
      for (int ni = 0; ni < 4; ++ni)
        acc[mi][ni] = __builtin_amdgcn_mfma_f32_16x16x32_f16(af[mi], bf[ni], acc[mi][ni], 0, 0, 0);
    __syncthreads();
  }

  const int mbase = m0 + wm * 64 + ((l >> 4) << 2);
  const int nbase = n0 + wn * 64 + (l & 15);
#pragma unroll
  for (int mi = 0; mi < 4; ++mi) {
#pragma unroll
    for (int ni = 0; ni < 4; ++ni) {
      int n = nbase + ni * 16;
      if (n < NVALID) {
        float bsv = bias[n];
#pragma unroll
        for (int q = 0; q < 4; ++q) {
          int m = mbase + mi * 16 + q;
          float v = acc[mi][ni][q] + bsv;
          if constexpr (OUTF16)
            reinterpret_cast<f16*>(Cout)[(size_t)m * LDC + n] = (f16)v;
          else
            reinterpret_cast<float*>(Cout)[(size_t)m * LDC + n] = v;
        }
      }
    }
  }
}

// ---------- global GRU scan, one TC-step chunk: 1 block/batch item, 768 thr ----------
// 12 waves => 3 waves/SIMD; VGPR cap 170; live set ~158 (128 weight regs + temps).
__global__ __launch_bounds__(768, 3) void gru_global_k(
    const u32* __restrict__ whh, const float* __restrict__ bhh,
    const f16* __restrict__ xbuf, u32* __restrict__ hseq,
    float* __restrict__ hstf, u32* __restrict__ hstp, int t0) {
  __shared__ alignas(16) u32 hpk[128];  // h packed f16 pairs (matvec input)
  __shared__ float hfs[256];            // fp32 master copy of h
  __shared__ float rz[512];             // r gates [0,256), z gates [256,512)
  const int b = blockIdx.x;
  const int r = threadIdx.x;

  u32 wv[128];
#pragma unroll
  for (int i = 0; i < 128; ++i) wv[i] = whh[i * 768 + r];
  const float bh = bhh[r];

  if (t0 == 0) {
    if (r < 256) hfs[r] = 0.f;
    if (r < 128) hpk[r] = 0u;
  } else {
    if (r < 256) hfs[r] = hstf[b * 256 + r];
    if (r < 128) hpk[r] = hstp[b * 128 + r];
  }
  __syncthreads();

  const f16* xp = xbuf + (size_t)b * 1152 + r;           // chunk rows are t-major
  u32* hout = hseq + (size_t)b * 512 * 128 + (size_t)t0 * 128;
  float xv = (float)xp[0];

  for (int t = 0; t < TC; ++t) {
    float xnext = 0.f;
    if (t < TC - 1) xnext = (float)xp[(size_t)(t + 1) * 256 * 1152];

    float a0 = 0.f, a1 = 0.f, a2 = 0.f, a3 = 0.f;
#pragma unroll
    for (int q = 0; q < 32; ++q) {
      uint4 hq = reinterpret_cast<const uint4*>(hpk)[q];  // wave-uniform -> broadcast
      a0 = dot2f(wv[4 * q + 0], hq.x, a0);
      a1 = dot2f(wv[4 * q + 1], hq.y, a1);
      a2 = dot2f(wv[4 * q + 2], hq.z, a2);
      a3 = dot2f(wv[4 * q + 3], hq.w, a3);
    }
    float gh = ((a0 + a1) + (a2 + a3)) + bh;

    if (r < 512) rz[r] = sigf(xv + gh);   // waves 0-7: r,z gates
    __syncthreads();
    if (r >= 512) {                        // waves 8-11: n gate + h update
      int j = r - 512;
      float rv = rz[j];
      float zv = rz[256 + j];
      float nv = tanhf_fast(xv + rv * gh);
      float hold = hfs[j];
      float hnew = (1.f - zv) * nv + zv * hold;
      hfs[j] = hnew;
      float hpart = __shfl_xor(hnew, 1, 64);
      if ((j & 1) == 0) {
        u32 packed = pk2f(hnew, hpart);
        hpk[j >> 1] = packed;
        hout[(size_t)t * 128 + (j >> 1)] = packed;
      }
    }
    __syncthreads();
    xv = xnext;
  }
  // persist h state for next chunk (loop ended with a barrier)
  if (r < 256) hstf[b * 256 + r] = hfs[r];
  if (r < 128) hstp[b * 128 + r] = hpk[r];
}

// ---------- local GRU scan chunk: 1 block/batch item, 384 thr ----------
__global__ __launch_bounds__(384, 2) void gru_local_k(
    const u32* __restrict__ whh, const float* __restrict__ bhh,
    const f16* __restrict__ xbuf, u32* __restrict__ hseq,
    float* __restrict__ hstf, u32* __restrict__ hstp, int t0) {
  __shared__ alignas(16) u32 hpk[64];
  __shared__ float hfs[128];
  __shared__ float rz[256];
  const int b = blockIdx.x;
  const int r = threadIdx.x;

  u32 wv[64];
#pragma unroll
  for (int i = 0; i < 64; ++i) wv[i] = whh[i * 384 + r];
  const float bh = bhh[r];

  if (t0 == 0) {
    if (r < 128) hfs[r] = 0.f;
    if (r < 64) hpk[r] = 0u;
  } else {
    if (r < 128) hfs[r] = hstf[b * 128 + r];
    if (r < 64) hpk[r] = hstp[b * 64 + r];
  }
  __syncthreads();

  const f16* xp = xbuf + (size_t)b * 1152 + 768 + r;
  u32* hout = hseq + (size_t)b * 512 * 64 + (size_t)t0 * 64;
  float xv = (float)xp[0];

  for (int t = 0; t < TC; ++t) {
    float xnext = 0.f;
    if (t < TC - 1) xnext = (float)xp[(size_t)(t + 1) * 256 * 1152];

    float a0 = 0.f, a1 = 0.f, a2 = 0.f, a3 = 0.f;
#pragma unroll
    for (int q = 0; q < 16; ++q) {
      uint4 hq = reinterpret_cast<const uint4*>(hpk)[q];
      a0 = dot2f(wv[4 * q + 0], hq.x, a0);
      a1 = dot2f(wv[4 * q + 1], hq.y, a1);
      a2 = dot2f(wv[4 * q + 2], hq.z, a2);
      a3 = dot2f(wv[4 * q + 3], hq.w, a3);
    }
    float gh = ((a0 + a1) + (a2 + a3)) + bh;

    if (r < 256) rz[r] = sigf(xv + gh);   // waves 0-3
    __syncthreads();
    if (r >= 256) {                        // waves 4-5
      int j = r - 256;
      float rv = rz[j];
      float zv = rz[128 + j];
      float nv = tanhf_fast(xv + rv * gh);
      float hold = hfs[j];
      float hnew = (1.f - zv) * nv + zv * hold;
      hfs[j] = hnew;
      float hpart = __shfl_xor(hnew, 1, 64);
      if ((j & 1) == 0) {
        u32 packed = pk2f(hnew, hpart);
        hpk[j >> 1] = packed;
        hout[(size_t)t * 64 + (j >> 1)] = packed;
      }
    }
    __syncthreads();
    xv = xnext;
  }
  if (r < 128) hstf[b * 128 + r] = hfs[r];
  if (r < 64) hstp[b * 64 + r] = hpk[r];
}

// ---------- launch ----------
extern "C" void kernel_launch(void* const* d_in, const int* in_sizes, int n_in,
                              void* d_out, int out_size, void* d_ws, size_t ws_size,
                              hipStream_t stream) {
  (void)in_sizes; (void)n_in; (void)out_size;
  if (ws_size < WS_NEED) return;  // tripwire: wrong results (not a fault) if ws too small
  const float* f_seq = (const float*)d_in[0];
  const float* delta = (const float*)d_in[1];
  const float* ovseq = (const float*)d_in[2];
  const float* W1 = (const float*)d_in[3];
  const float* b1 = (const float*)d_in[4];
  const float* W2 = (const float*)d_in[5];
  const float* b2 = (const float*)d_in[6];
  const float* Wih_g = (const float*)d_in[7];
  const float* Whh_g = (const float*)d_in[8];
  const float* bih_g = (const float*)d_in[9];
  const float* bhh_g = (const float*)d_in[10];
  const float* Wih_l = (const float*)d_in[11];
  const float* Whh_l = (const float*)d_in[12];
  const float* bih_l = (const float*)d_in[13];
  const float* bhh_l = (const float*)d_in[14];
  const float* Wg = (const float*)d_in[15];
  const float* bg = (const float*)d_in[16];
  const float* Wl = (const float*)d_in[17];
  const float* bl = (const float*)d_in[18];

  char* ws = (char*)d_ws;
  f16* inp = (f16*)(ws + O_INP);
  f16* xbuf = (f16*)(ws + O_XB);
  f16* hg16 = (f16*)(ws + O_HG);
  f16* hl16 = (f16*)(ws + O_HL);
  f16* wfused = (f16*)(ws + O_WF);
  float* biasf = (float*)(ws + O_BF);
  u32* whhg = (u32*)(ws + O_WHG);
  u32* whhl = (u32*)(ws + O_WHL);
  f16* wg16 = (f16*)(ws + O_WG);
  f16* wl16 = (f16*)(ws + O_WL);
  float* hgf = (float*)(ws + O_HGF);
  u32* hgp = (u32*)(ws + O_HGP);
  float* hlf = (float*)(ws + O_HLF);
  u32* hlp = (u32*)(ws + O_HLP);

  float* outg = (float*)d_out;
  float* outm = outg + NROWS * 128;

  prep_k<<<dim3(256), dim3(256), 0, stream>>>(Wih_g, Wih_l, bih_g, bih_l, Whh_g, Whh_l,
                                              Wg, Wl, wfused, biasf, whhg, whhl, wg16, wl16);
  encoder_k<<<dim3(512), dim3(256), 0, stream>>>(f_seq, delta, ovseq, W1, b1, W2, b2, inp);

  for (int c = 0; c < NCHUNK; ++c) {
    const f16* Ac = inp + (size_t)c * CROWS * 192;
    // xbuf = inp_chunk @ wfused^T + biasf   (M=16384, N=1152, K=192) -> f16
    gemm_f16k<192, 1152, 1152, true, 1152><<<dim3(9, CROWS / 128), dim3(256), 0, stream>>>(
        Ac, wfused, biasf, xbuf);
    gru_global_k<<<dim3(256), dim3(768), 0, stream>>>(whhg, bhh_g, xbuf, (u32*)hg16, hgf, hgp, c * TC);
    gru_local_k<<<dim3(256), dim3(384), 0, stream>>>(whhl, bhh_l, xbuf, (u32*)hl16, hlf, hlp, c * TC);
  }

  // g = hg @ Wg^T + bg   (M=131072, N=128, K=256) -> f32
  gemm_f16k<256, 128, 128, false, 128><<<dim3(1, 1024), dim3(256), 0, stream>>>(hg16, wg16, bg, outg);
  // m = hl @ Wl^T + bl   (M=131072, N=64, K=128) -> f32
  gemm_f16k<128, 64, 64, false, 64><<<dim3(1, 1024), dim3(256), 0, stream>>>(hl16, wl16, bl, outm);
}

// Round 5
// 1611.833 us; speedup vs baseline: 1.0743x; 1.0743x over previous
//
#include <hip/hip_runtime.h>

typedef _Float16 f16;
typedef _Float16 f16x2 __attribute__((ext_vector_type(2)));
typedef _Float16 f16x8 __attribute__((ext_vector_type(8)));
typedef float f32x4 __attribute__((ext_vector_type(4)));
typedef unsigned int u32;

// ---------- sizes ----------
// B=256, W=512, FEAT=128, TIME=32, OV=32, IN=192, HG=256, HL=128, OG=128, OL=64
// rows = B*W = 131072. Time processed in NCHUNK chunks of TC steps.
static constexpr size_t NROWS = 131072;
static constexpr int TC = 64;
static constexpr int NCHUNK = 8;   // 512 / TC
static constexpr size_t CROWS = 256 * TC;  // rows per chunk = 16384

// inp is B-MAJOR: row (b*512 + t), 192 f16 each (96 u32: 0-63 f, 64-79 delta, 80-95 ov).
// xbuf rows are m-order: m = tt*256 + b (tt = t within chunk). GEMM remaps A rows.
static constexpr size_t O_INP = 0;                                   // inp f16 [131072][192] b-major
static constexpr size_t SZ_INP = NROWS * 192 * 2;                    // 50.3 MB
static constexpr size_t O_XB  = O_INP + SZ_INP;                      // xih chunk f16 [16384][1152]
static constexpr size_t SZ_XB = CROWS * 1152 * 2;                    // 37.7 MB
static constexpr size_t O_HG  = O_XB + SZ_XB;                        // hg_seq f16 [131072][256] b-major
static constexpr size_t SZ_HG = NROWS * 256 * 2;                     // 67.1 MB
static constexpr size_t O_HL  = O_HG + SZ_HG;                        // hl_seq f16 [131072][128] b-major
static constexpr size_t SZ_HL = NROWS * 128 * 2;                     // 33.6 MB
static constexpr size_t O_WF  = O_HL + SZ_HL;                        // wfused f16 [1152][192]
static constexpr size_t SZ_WF = 1152 * 192 * 2;
static constexpr size_t O_BF  = O_WF + SZ_WF;                        // biasf f32 [1152]
static constexpr size_t SZ_BF = 1152 * 4;
static constexpr size_t O_WHG = O_BF + SZ_BF;                        // whh_g packed [128][768] u32
static constexpr size_t SZ_WHG = 128 * 768 * 4;
static constexpr size_t O_WHL = O_WHG + SZ_WHG;                      // whh_l packed [64][384] u32
static constexpr size_t SZ_WHL = 64 * 384 * 4;
static constexpr size_t O_WG  = O_WHL + SZ_WHL;                      // wg f16 [128][256]
static constexpr size_t SZ_WG = 128 * 256 * 2;
static constexpr size_t O_WL  = O_WG + SZ_WG;                        // wl f16 [64][128]
static constexpr size_t SZ_WL = 64 * 128 * 2;
static constexpr size_t O_HGF = O_WL + SZ_WL;                        // h-state global f32 [256][256]
static constexpr size_t SZ_HGF = 256 * 256 * 4;
static constexpr size_t O_HGP = O_HGF + SZ_HGF;                      // h-state global packed u32 [256][128]
static constexpr size_t SZ_HGP = 256 * 128 * 4;
static constexpr size_t O_HLF = O_HGP + SZ_HGP;                      // h-state local f32 [256][128]
static constexpr size_t SZ_HLF = 256 * 128 * 4;
static constexpr size_t O_HLP = O_HLF + SZ_HLF;                      // h-state local packed u32 [256][64]
static constexpr size_t SZ_HLP = 256 * 64 * 4;
static constexpr size_t WS_NEED = O_HLP + SZ_HLP;                    // ~181.5 MiB

// ---------- helpers ----------
__device__ inline u32 pk2f(float lo, float hi) {
  f16x2 t; t.x = (f16)lo; t.y = (f16)hi;
  return __builtin_bit_cast(u32, t);
}

#if defined(__has_builtin)
#if __has_builtin(__builtin_amdgcn_fdot2)
#define HAVE_FDOT2 1
#endif
#endif

__device__ inline float dot2f(u32 w, u32 h, float c) {
#ifdef HAVE_FDOT2
  return __builtin_amdgcn_fdot2(__builtin_bit_cast(f16x2, w),
                                __builtin_bit_cast(f16x2, h), c, false);
#else
  f16x2 a = __builtin_bit_cast(f16x2, w);
  f16x2 b = __builtin_bit_cast(f16x2, h);
  return c + (float)a.x * (float)b.x + (float)a.y * (float)b.y;
#endif
}

__device__ inline float sigf(float x) { return 1.f / (1.f + __expf(-x)); }
__device__ inline float tanhf_fast(float x) { return 1.f - 2.f / (1.f + __expf(2.f * x)); }

// ---------- prep: weight conversion/packing ----------
__global__ void prep_k(const float* __restrict__ Wih_g, const float* __restrict__ Wih_l,
                       const float* __restrict__ bih_g, const float* __restrict__ bih_l,
                       const float* __restrict__ Whh_g, const float* __restrict__ Whh_l,
                       const float* __restrict__ Wg, const float* __restrict__ Wl,
                       f16* __restrict__ wfused, float* __restrict__ biasf,
                       u32* __restrict__ whhg, u32* __restrict__ whhl,
                       f16* __restrict__ wg16, f16* __restrict__ wl16) {
  const int tid = blockIdx.x * blockDim.x + threadIdx.x;
  const int stride = gridDim.x * blockDim.x;
  for (int i = tid; i < 1152 * 192; i += stride) {
    int r = i / 192;
    wfused[i] = (f16)(r < 768 ? Wih_g[i] : Wih_l[i - 768 * 192]);
  }
  for (int i = tid; i < 1152; i += stride)
    biasf[i] = (i < 768) ? bih_g[i] : bih_l[i - 768];
  for (int i = tid; i < 128 * 768; i += stride) {
    int k2 = i / 768, r = i % 768;
    whhg[i] = pk2f(Whh_g[r * 256 + 2 * k2], Whh_g[r * 256 + 2 * k2 + 1]);
  }
  for (int i = tid; i < 64 * 384; i += stride) {
    int k2 = i / 384, r = i % 384;
    whhl[i] = pk2f(Whh_l[r * 128 + 2 * k2], Whh_l[r * 128 + 2 * k2 + 1]);
  }
  for (int i = tid; i < 128 * 256; i += stride) wg16[i] = (f16)Wg[i];
  for (int i = tid; i < 64 * 128; i += stride) wl16[i] = (f16)Wl[i];
}

// ---------- copy f_seq -> inp cols 0..63 (u32), fully coalesced ----------
__global__ __launch_bounds__(256) void copy_f_k(const float* __restrict__ f_seq,
                                                f16* __restrict__ inp) {
  const size_t idx = (size_t)blockIdx.x * 256 + threadIdx.x;  // over NROWS*32 float4s
  const float4 v = reinterpret_cast<const float4*>(f_seq)[idx];
  const size_t row = idx >> 5, c4 = idx & 31;
  uint2 pr; pr.x = pk2f(v.x, v.y); pr.y = pk2f(v.z, v.w);
  *reinterpret_cast<uint2*>(reinterpret_cast<u32*>(inp) + row * 96 + 2 * c4) = pr;
}

// ---------- copy delta -> inp cols 64..79 ----------
__global__ __launch_bounds__(256) void copy_d_k(const float* __restrict__ delta,
                                                f16* __restrict__ inp) {
  const size_t idx = (size_t)blockIdx.x * 256 + threadIdx.x;  // over NROWS*8 float4s
  const float4 v = reinterpret_cast<const float4*>(delta)[idx];
  const size_t row = idx >> 3, c4 = idx & 7;
  uint2 pr; pr.x = pk2f(v.x, v.y); pr.y = pk2f(v.z, v.w);
  *reinterpret_cast<uint2*>(reinterpret_cast<u32*>(inp) + row * 96 + 64 + 2 * c4) = pr;
}

// ---------- ov encoder: silu(ov@W1^T+b1)@W2^T+b2 -> inp cols 80..95 ----------
__global__ __launch_bounds__(256) void ovenc_k(
    const float* __restrict__ ovin, const float* __restrict__ W1,
    const float* __restrict__ b1, const float* __restrict__ W2,
    const float* __restrict__ b2, f16* __restrict__ inp) {
  __shared__ float sW1[2048], sW2[2048], sb1[64], sb2[32];
  for (int i = threadIdx.x; i < 2048; i += 256) { sW1[i] = W1[i]; sW2[i] = W2[i]; }
  if (threadIdx.x < 64) sb1[threadIdx.x] = b1[threadIdx.x];
  if (threadIdx.x < 32) sb2[threadIdx.x] = b2[threadIdx.x];
  __syncthreads();
  const size_t row = (size_t)blockIdx.x * 256 + threadIdx.x;  // b-major row

  float ov[32];
  const float4* ovp = reinterpret_cast<const float4*>(ovin + row * 32);
#pragma unroll
  for (int i = 0; i < 8; ++i) {
    float4 v = ovp[i];
    ov[4 * i] = v.x; ov[4 * i + 1] = v.y; ov[4 * i + 2] = v.z; ov[4 * i + 3] = v.w;
  }
  float hb[64];
#pragma unroll
  for (int j = 0; j < 64; ++j) {
    float s = sb1[j];
#pragma unroll
    for (int k = 0; k < 32; ++k) s += sW1[j * 32 + k] * ov[k];
    hb[j] = s * sigf(s);   // SiLU
  }
  u32* orow = reinterpret_cast<u32*>(inp) + row * 96 + 80;
#pragma unroll
  for (int p = 0; p < 16; ++p) {
    float s0 = sb2[2 * p], s1 = sb2[2 * p + 1];
#pragma unroll
    for (int j = 0; j < 64; ++j) {
      s0 += sW2[(2 * p) * 64 + j] * hb[j];
      s1 += sW2[(2 * p + 1) * 64 + j] * hb[j];
    }
    orow[p] = pk2f(s0, s1);
  }
}

// ---------- MFMA f16 GEMM: C[M][N] = A[rows][K] @ Bw[N][K]^T + bias ----------
// 128x128 tile, 256 threads (4 waves, 2x2), padded LDS stride 40 halves (80B).
// REMAP: logical row m -> physical A row (m&255)*512 + t_base + (m>>8)  (b-major inp).
template <int K, int NROWSB, int NVALID, bool OUTF16, int LDC, bool REMAP>
__global__ __launch_bounds__(256, 2) void gemm_f16k(
    const f16* __restrict__ A, const f16* __restrict__ Bw,
    const float* __restrict__ bias, void* __restrict__ Cout, int t_base) {
  __shared__ alignas(16) f16 At[128 * 40];
  __shared__ alignas(16) f16 Bt[128 * 40];
  const int n0 = blockIdx.x * 128;
  const int m0 = blockIdx.y * 128;
  const int tid = threadIdx.x;
  const int l = tid & 63;
  const int w = tid >> 6;
  const int wm = w >> 1, wn = w & 1;
  const int srow = tid >> 2, schunk = tid & 3;

  f32x4 acc[4][4] = {};

  for (int k0 = 0; k0 < K; k0 += 32) {
#pragma unroll
    for (int hh = 0; hh < 2; ++hh) {
      int row = srow + hh * 64;
      int m = m0 + row;
      size_t g = REMAP ? ((size_t)(m & 255) * 512 + (size_t)t_base + (size_t)(m >> 8))
                       : (size_t)m;
      uint4 av = *reinterpret_cast<const uint4*>(A + g * K + k0 + schunk * 8);
      *reinterpret_cast<uint4*>(&At[row * 40 + schunk * 8]) = av;
      int nr = n0 + row;
      uint4 bv = make_uint4(0u, 0u, 0u, 0u);
      if (nr < NROWSB)
        bv = *reinterpret_cast<const uint4*>(Bw + (size_t)nr * K + k0 + schunk * 8);
      *reinterpret_cast<uint4*>(&Bt[row * 40 + schunk * 8]) = bv;
    }
    __syncthreads();
    f16x8 af[4], bf[4];
#pragma unroll
    for (int i = 0; i < 4; ++i) {
      af[i] = *reinterpret_cast<const f16x8*>(&At[(wm * 64 + i * 16 + (l & 15)) * 40 + (l >> 4) * 8]);
      bf[i] = *reinterpret_cast<const f16x8*>(&Bt[(wn * 64 + i * 16 + (l & 15)) * 40 + (l >> 4) * 8]);
    }
#pragma unroll
    for (int mi = 0; mi < 4; ++mi)
#pragma unroll
      for (int ni = 0; ni < 4; ++ni)
        acc[mi][ni] = __builtin_amdgcn_mfma_f32_16x16x32_f16(af[mi], bf[ni], acc[mi][ni], 0, 0, 0);
    __syncthreads();
  }

  const int mbase = m0 + wm * 64 + ((l >> 4) << 2);
  const int nbase = n0 + wn * 64 + (l & 15);
#pragma unroll
  for (int mi = 0; mi < 4; ++mi) {
#pragma unroll
    for (int ni = 0; ni < 4; ++ni) {
      int n = nbase + ni * 16;
      if (n < NVALID) {
        float bsv = bias[n];
#pragma unroll
        for (int q = 0; q < 4; ++q) {
          int m = mbase + mi * 16 + q;
          float v = acc[mi][ni][q] + bsv;
          if constexpr (OUTF16)
            reinterpret_cast<f16*>(Cout)[(size_t)m * LDC + n] = (f16)v;
          else
            reinterpret_cast<float*>(Cout)[(size_t)m * LDC + n] = v;
        }
      }
    }
  }
}

// ---------- global GRU scan, one TC-step chunk: 1 block/batch item, 768 thr ----------
// 12 waves => 3 waves/SIMD; VGPR cap 170; live set ~158 (128 weight regs + temps).
__global__ __launch_bounds__(768, 3) void gru_global_k(
    const u32* __restrict__ whh, const float* __restrict__ bhh,
    const f16* __restrict__ xbuf, u32* __restrict__ hseq,
    float* __restrict__ hstf, u32* __restrict__ hstp, int t0) {
  __shared__ alignas(16) u32 hpk[128];  // h packed f16 pairs (matvec input)
  __shared__ float hfs[256];            // fp32 master copy of h
  __shared__ float rz[512];             // r gates [0,256), z gates [256,512)
  const int b = blockIdx.x;
  const int r = threadIdx.x;

  u32 wv[128];
#pragma unroll
  for (int i = 0; i < 128; ++i) wv[i] = whh[i * 768 + r];
  const float bh = bhh[r];

  if (t0 == 0) {
    if (r < 256) hfs[r] = 0.f;
    if (r < 128) hpk[r] = 0u;
  } else {
    if (r < 256) hfs[r] = hstf[b * 256 + r];
    if (r < 128) hpk[r] = hstp[b * 128 + r];
  }
  __syncthreads();

  const f16* xp = xbuf + (size_t)b * 1152 + r;           // chunk rows are m-order
  u32* hout = hseq + (size_t)b * 512 * 128 + (size_t)t0 * 128;
  float xv = (float)xp[0];

  for (int t = 0; t < TC; ++t) {
    float xnext = 0.f;
    if (t < TC - 1) xnext = (float)xp[(size_t)(t + 1) * 256 * 1152];

    float a0 = 0.f, a1 = 0.f, a2 = 0.f, a3 = 0.f;
#pragma unroll
    for (int q = 0; q < 32; ++q) {
      uint4 hq = reinterpret_cast<const uint4*>(hpk)[q];  // wave-uniform -> broadcast
      a0 = dot2f(wv[4 * q + 0], hq.x, a0);
      a1 = dot2f(wv[4 * q + 1], hq.y, a1);
      a2 = dot2f(wv[4 * q + 2], hq.z, a2);
      a3 = dot2f(wv[4 * q + 3], hq.w, a3);
    }
    float gh = ((a0 + a1) + (a2 + a3)) + bh;

    if (r < 512) rz[r] = sigf(xv + gh);   // waves 0-7: r,z gates
    __syncthreads();
    if (r >= 512) {                        // waves 8-11: n gate + h update
      int j = r - 512;
      float rv = rz[j];
      float zv = rz[256 + j];
      float nv = tanhf_fast(xv + rv * gh);
      float hold = hfs[j];
      float hnew = (1.f - zv) * nv + zv * hold;
      hfs[j] = hnew;
      float hpart = __shfl_xor(hnew, 1, 64);
      if ((j & 1) == 0) {
        u32 packed = pk2f(hnew, hpart);
        hpk[j >> 1] = packed;
        hout[(size_t)t * 128 + (j >> 1)] = packed;
      }
    }
    __syncthreads();
    xv = xnext;
  }
  // persist h state for next chunk (loop ended with a barrier)
  if (r < 256) hstf[b * 256 + r] = hfs[r];
  if (r < 128) hstp[b * 128 + r] = hpk[r];
}

// ---------- local GRU scan chunk: 1 block/batch item, 384 thr ----------
__global__ __launch_bounds__(384, 2) void gru_local_k(
    const u32* __restrict__ whh, const float* __restrict__ bhh,
    const f16* __restrict__ xbuf, u32* __restrict__ hseq,
    float* __restrict__ hstf, u32* __restrict__ hstp, int t0) {
  __shared__ alignas(16) u32 hpk[64];
  __shared__ float hfs[128];
  __shared__ float rz[256];
  const int b = blockIdx.x;
  const int r = threadIdx.x;

  u32 wv[64];
#pragma unroll
  for (int i = 0; i < 64; ++i) wv[i] = whh[i * 384 + r];
  const float bh = bhh[r];

  if (t0 == 0) {
    if (r < 128) hfs[r] = 0.f;
    if (r < 64) hpk[r] = 0u;
  } else {
    if (r < 128) hfs[r] = hstf[b * 128 + r];
    if (r < 64) hpk[r] = hstp[b * 64 + r];
  }
  __syncthreads();

  const f16* xp = xbuf + (size_t)b * 1152 + 768 + r;
  u32* hout = hseq + (size_t)b * 512 * 64 + (size_t)t0 * 64;
  float xv = (float)xp[0];

  for (int t = 0; t < TC; ++t) {
    float xnext = 0.f;
    if (t < TC - 1) xnext = (float)xp[(size_t)(t + 1) * 256 * 1152];

    float a0 = 0.f, a1 = 0.f, a2 = 0.f, a3 = 0.f;
#pragma unroll
    for (int q = 0; q < 16; ++q) {
      uint4 hq = reinterpret_cast<const uint4*>(hpk)[q];
      a0 = dot2f(wv[4 * q + 0], hq.x, a0);
      a1 = dot2f(wv[4 * q + 1], hq.y, a1);
      a2 = dot2f(wv[4 * q + 2], hq.z, a2);
      a3 = dot2f(wv[4 * q + 3], hq.w, a3);
    }
    float gh = ((a0 + a1) + (a2 + a3)) + bh;

    if (r < 256) rz[r] = sigf(xv + gh);   // waves 0-3
    __syncthreads();
    if (r >= 256) {                        // waves 4-5
      int j = r - 256;
      float rv = rz[j];
      float zv = rz[128 + j];
      float nv = tanhf_fast(xv + rv * gh);
      float hold = hfs[j];
      float hnew = (1.f - zv) * nv + zv * hold;
      hfs[j] = hnew;
      float hpart = __shfl_xor(hnew, 1, 64);
      if ((j & 1) == 0) {
        u32 packed = pk2f(hnew, hpart);
        hpk[j >> 1] = packed;
        hout[(size_t)t * 64 + (j >> 1)] = packed;
      }
    }
    __syncthreads();
    xv = xnext;
  }
  if (r < 128) hstf[b * 128 + r] = hfs[r];
  if (r < 64) hstp[b * 64 + r] = hpk[r];
}

// ---------- launch ----------
extern "C" void kernel_launch(void* const* d_in, const int* in_sizes, int n_in,
                              void* d_out, int out_size, void* d_ws, size_t ws_size,
                              hipStream_t stream) {
  (void)in_sizes; (void)n_in; (void)out_size;
  if (ws_size < WS_NEED) return;  // tripwire: wrong results (not a fault) if ws too small
  const float* f_seq = (const float*)d_in[0];
  const float* delta = (const float*)d_in[1];
  const float* ovseq = (const float*)d_in[2];
  const float* W1 = (const float*)d_in[3];
  const float* b1 = (const float*)d_in[4];
  const float* W2 = (const float*)d_in[5];
  const float* b2 = (const float*)d_in[6];
  const float* Wih_g = (const float*)d_in[7];
  const float* Whh_g = (const float*)d_in[8];
  const float* bih_g = (const float*)d_in[9];
  const float* bhh_g = (const float*)d_in[10];
  const float* Wih_l = (const float*)d_in[11];
  const float* Whh_l = (const float*)d_in[12];
  const float* bih_l = (const float*)d_in[13];
  const float* bhh_l = (const float*)d_in[14];
  const float* Wg = (const float*)d_in[15];
  const float* bg = (const float*)d_in[16];
  const float* Wl = (const float*)d_in[17];
  const float* bl = (const float*)d_in[18];

  char* ws = (char*)d_ws;
  f16* inp = (f16*)(ws + O_INP);
  f16* xbuf = (f16*)(ws + O_XB);
  f16* hg16 = (f16*)(ws + O_HG);
  f16* hl16 = (f16*)(ws + O_HL);
  f16* wfused = (f16*)(ws + O_WF);
  float* biasf = (float*)(ws + O_BF);
  u32* whhg = (u32*)(ws + O_WHG);
  u32* whhl = (u32*)(ws + O_WHL);
  f16* wg16 = (f16*)(ws + O_WG);
  f16* wl16 = (f16*)(ws + O_WL);
  float* hgf = (float*)(ws + O_HGF);
  u32* hgp = (u32*)(ws + O_HGP);
  float* hlf = (float*)(ws + O_HLF);
  u32* hlp = (u32*)(ws + O_HLP);

  float* outg = (float*)d_out;
  float* outm = outg + NROWS * 128;

  prep_k<<<dim3(256), dim3(256), 0, stream>>>(Wih_g, Wih_l, bih_g, bih_l, Whh_g, Whh_l,
                                              Wg, Wl, wfused, biasf, whhg, whhl, wg16, wl16);
  copy_f_k<<<dim3(NROWS * 32 / 256), dim3(256), 0, stream>>>(f_seq, inp);
  copy_d_k<<<dim3(NROWS * 8 / 256), dim3(256), 0, stream>>>(delta, inp);
  ovenc_k<<<dim3(512), dim3(256), 0, stream>>>(ovseq, W1, b1, W2, b2, inp);

  for (int c = 0; c < NCHUNK; ++c) {
    // xbuf = inp_chunk @ wfused^T + biasf   (M=16384, N=1152, K=192) -> f16
    gemm_f16k<192, 1152, 1152, true, 1152, true><<<dim3(9, CROWS / 128), dim3(256), 0, stream>>>(
        inp, wfused, biasf, xbuf, c * TC);
    gru_global_k<<<dim3(256), dim3(768), 0, stream>>>(whhg, bhh_g, xbuf, (u32*)hg16, hgf, hgp, c * TC);
    gru_local_k<<<dim3(256), dim3(384), 0, stream>>>(whhl, bhh_l, xbuf, (u32*)hl16, hlf, hlp, c * TC);
  }

  // g = hg @ Wg^T + bg   (M=131072, N=128, K=256) -> f32
  gemm_f16k<256, 128, 128, false, 128, false><<<dim3(1, 1024), dim3(256), 0, stream>>>(hg16, wg16, bg, outg, 0);
  // m = hl @ Wl^T + bl   (M=131072, N=64, K=128) -> f32
  gemm_f16k<128, 64, 64, false, 64, false><<<dim3(1, 1024), dim3(256), 0, stream>>>(hl16, wl16, bl, outm, 0);
}